// Round 14
// baseline (56.523 us; speedup 1.0000x reference)
//
#include <hip/hip_runtime.h>

#define SB 32      // batch
#define SS 2048    // sequence
#define SH 2       // heads
#define SD 4       // head dim
#define SE 8       // embed
#define BHS (SB * SH * SS)

#define JCH  2               // j-chunks (key split) per (b,h)
#define JLEN (SS / JCH)      // 1024 keys per block
#define NT   (JLEN / 32)     // 32 j-tiles per wave

#define LOG2E 1.44269504f

typedef float    f32x16 __attribute__((ext_vector_type(16)));
typedef _Float16 f16x8  __attribute__((ext_vector_type(8)));

static __device__ __forceinline__ float fast_exp2(float x) {
#if __has_builtin(__builtin_amdgcn_exp2f)
    return __builtin_amdgcn_exp2f(x);
#else
    return exp2f(x);
#endif
}

static __device__ __forceinline__ int cvtpk(float a, float b) {
    auto h = __builtin_amdgcn_cvt_pkrtz(a, b);
    union { decltype(h) hh; int i; } u; u.hh = h; return u.i;
}

// exchange register halves across the lane<32 / lane>=32 boundary
static __device__ __forceinline__ void swap32(int a, int b, int lane, int& r0, int& r1) {
#if __has_builtin(__builtin_amdgcn_permlane32_swap)
    auto r = __builtin_amdgcn_permlane32_swap(a, b, false, false);
    r0 = r[0]; r1 = r[1];
#else
    const int blo = __builtin_amdgcn_ds_bpermute((lane & 31) << 2, b);
    const int ahi = __builtin_amdgcn_ds_bpermute(((lane ^ 32) & 63) << 2, a);
    r0 = (lane < 32) ? a : blo;
    r1 = (lane < 32) ? ahi : b;
#endif
}

static __device__ __forceinline__ f16x8 frag2(unsigned x, unsigned y) {
    union { unsigned u[4]; f16x8 h; } c;
    c.u[0] = x; c.u[1] = y; c.u[2] = 0; c.u[3] = 0; return c.h;
}
static __device__ __forceinline__ f16x8 frag4(uint4 v) {
    union { uint4 u; f16x8 h; } c; c.u = v; return c.h;
}
static __device__ __forceinline__ f16x8 fragi(int a, int b, int c_, int d) {
    union { int u[4]; f16x8 h; } c;
    c.u[0] = a; c.u[1] = b; c.u[2] = c_; c.u[3] = d; return c.h;
}

union u32h2 { unsigned u; _Float16 h[2]; };
static __device__ __forceinline__ unsigned packh2(float a, float b) {
    u32h2 c; c.h[0] = (_Float16)a; c.h[1] = (_Float16)b; return c.u;
}

// ---------------------------------------------------------------------------
// Kernel 1: moving averages + QKV projection. q (pre-scaled by log2e/sqrt(D))
// and k packed to f16 (uint2/row); V written TRANSPOSED as f16 rows
// VTg[bh][c=0..3][s]. No softmax shift anywhere: it cancels exactly in
// O~/l, and scores are small enough that exp2 stays in f32/f16 range.
// ---------------------------------------------------------------------------
__global__ __launch_bounds__(256) void k_ma_qkv(
    const float* __restrict__ x,      // [B,S]
    const float* __restrict__ Wq,     // [4,4] row-major W[e*4+d]
    const float* __restrict__ Wk,
    const float* __restrict__ Wv,
    uint2* __restrict__ qws16,        // [B*H*S] packed f16 {q01,q23}
    uint2* __restrict__ kws16,        // [B*H*S]
    _Float16* __restrict__ vtg,       // [B*H][4][S] V transposed, f16
    float4* __restrict__ mmws)        // [B*S*2]
{
    __shared__ float xs[272];

    const int tile = blockIdx.x % (SS / 256);
    const int b    = blockIdx.x / (SS / 256);
    const int s0   = tile * 256;
    const float* xrow = x + b * SS;

    for (int i = threadIdx.x; i < 272; i += 256) {
        int idx = s0 - 8 + i;
        idx = min(max(idx, 0), SS - 1);
        xs[i] = xrow[idx];
    }
    __syncthreads();

    const int t = threadIdx.x;
    const int s = s0 + t;

    float mmv[8];
    float c = xs[8 + t];
    #pragma unroll
    for (int h = 1; h <= 8; ++h) {
        c += xs[8 + t - h] + xs[8 + t + h];
        mmv[h - 1] = c * (1.0f / (float)(2 * h + 1));
    }

    mmws[(b * SS + s) * 2 + 0] = make_float4(mmv[0], mmv[1], mmv[2], mmv[3]);
    mmws[(b * SS + s) * 2 + 1] = make_float4(mmv[4], mmv[5], mmv[6], mmv[7]);

    const float qscale = 0.5f * LOG2E;  // 1/sqrt(D) * log2(e)
    #pragma unroll
    for (int h = 0; h < SH; ++h) {
        const float t0 = mmv[h * 4 + 0];
        const float t1 = mmv[h * 4 + 1];
        const float t2 = mmv[h * 4 + 2];
        const float t3 = mmv[h * 4 + 3];
        float q[4], k[4], v[4];
        #pragma unroll
        for (int e = 0; e < 4; ++e) {
            q[e] = (t0 * Wq[e * 4 + 0] + t1 * Wq[e * 4 + 1] +
                    t2 * Wq[e * 4 + 2] + t3 * Wq[e * 4 + 3]) * qscale;
            k[e] =  t0 * Wk[e * 4 + 0] + t1 * Wk[e * 4 + 1] +
                    t2 * Wk[e * 4 + 2] + t3 * Wk[e * 4 + 3];
            v[e] =  t0 * Wv[e * 4 + 0] + t1 * Wv[e * 4 + 1] +
                    t2 * Wv[e * 4 + 2] + t3 * Wv[e * 4 + 3];
        }
        const int bh  = b * SH + h;
        const int idx = bh * SS + s;
        qws16[idx] = make_uint2(packh2(q[0], q[1]), packh2(q[2], q[3]));
        kws16[idx] = make_uint2(packh2(k[0], k[1]), packh2(k[2], k[3]));
        #pragma unroll
        for (int e = 0; e < 4; ++e)
            vtg[(bh * 4 + e) * SS + s] = (_Float16)v[e];
    }
}

// ---------------------------------------------------------------------------
// Kernel 2: MFMA flash attention, j-split for occupancy. R13 was
// latency-bound (MfmaUtil 21 / VALU ~23 / LDS ~28 per-SIMD — nothing
// saturated; 4 waves/SIMD can't cover the per-tile serial chain).
// Halving the staged K/V (LDS 37->18.6 KB) doubles residency to
// 8 blocks/CU = 8 waves/SIMD. Each block: 4 waves x one 32-row q-block,
// over JLEN=1024 keys. Writes unnormalized (O~, l) per chunk; plain-sum
// merge in the epilogue (no shift -> exact).
//   S^T = mfma(A=K-tile, B=Q); P~ = exp2(S^T);
//   O~^T += mfma(A=V^T(+ones row -> l), B=P~ via cvt_pkrtz+permlane32_swap)
// Grid = B*H * 16 * JCH = 2048 blocks.
// ---------------------------------------------------------------------------
#define LDS_K     0
#define K_BYTES   (JLEN * 8)              // 8192
#define LDS_VT    K_BYTES                 // 8192
#define VT_STRIDE ((JLEN + 8) * 2)        // 2064 B per V^T row
#define LDS_Z     (LDS_VT + 5 * VT_STRIDE)  // 18512 (16-aligned)
#define LDS_SIZE  (LDS_Z + 128)

__global__ __launch_bounds__(256, 8) void k_attn(
    const uint2* __restrict__ qws16,
    const uint2* __restrict__ kws16,
    const unsigned* __restrict__ vtg,   // u32 view of VT f16 [bh][4][SS]
    float4* __restrict__ pacc,          // [JCH][B*H*S] unnormalized O~
    float* __restrict__ pl)             // [JCH][B*H*S] l = sum P~
{
    __shared__ __align__(16) char lds[LDS_SIZE];

    const int t    = threadIdx.x;
    const int jc   = blockIdx.x & (JCH - 1);
    const int ig   = (blockIdx.x >> 1) & 15;
    const int bh   = blockIdx.x >> 5;
    const int w    = t >> 6;
    const int iblock = ig * 4 + w;
    const int lane = t & 63;
    const int c31  = lane & 31;

    // ---- stage K chunk (8 KB) ----
    const uint2* kg = kws16 + bh * SS + jc * JLEN;
    for (int i = t; i < JLEN; i += 256)
        *(uint2*)(lds + LDS_K + i * 8) = kg[i];
    // ---- stage V^T rows 0..3 (f16, padded row stride) ----
    const unsigned* vg = vtg + bh * 4 * (SS / 2) + jc * (JLEN / 2);
    for (int i = t; i < 4 * (JLEN / 2); i += 256) {
        const int cc = i / (JLEN / 2), col = i % (JLEN / 2);
        *(unsigned*)(lds + LDS_VT + cc * VT_STRIDE + col * 4) = vg[cc * (SS / 2) + col];
    }
    // ---- ones row (c = 4) -> l accumulator ----
    for (int i = t; i < JLEN / 2; i += 256)
        *(unsigned*)(lds + LDS_VT + 4 * VT_STRIDE + i * 4) = 0x3C003C00u;
    // ---- zero slot for padded lanes ----
    if (t < 32) *(unsigned*)(lds + LDS_Z + t * 4) = 0u;
    __syncthreads();

    // Q B-frag: lane holds col i=lane&31, k=d (lanes>=32 pad 0)
    uint2 qq = qws16[bh * SS + iblock * 32 + c31];
    if (lane >= 32) { qq.x = 0u; qq.y = 0u; }
    const f16x8 bq = frag2(qq.x, qq.y);

    int kaddr = (lane < 32) ? (LDS_K + lane * 8) : LDS_Z;
    const int kstep = (lane < 32) ? 256 : 0;            // 32 keys * 8 B
    int vaddr = (c31 < 5) ? (LDS_VT + c31 * VT_STRIDE + (lane >> 5) * 16) : LDS_Z;
    const int vstep = (c31 < 5) ? 64 : 0;               // 32 j * 2 B

    f32x16 oacc = {0,0,0,0,0,0,0,0,0,0,0,0,0,0,0,0};
    const f32x16 zc = {0,0,0,0,0,0,0,0,0,0,0,0,0,0,0,0};

    uint2 kk  = *(const uint2*)(lds + kaddr); kaddr += kstep;
    uint4 vv0 = *(const uint4*)(lds + vaddr);
    uint4 vv1 = *(const uint4*)(lds + vaddr + 32); vaddr += vstep;

    for (int jt = 0; jt < NT; ++jt) {
        const f16x8 ak  = frag2(kk.x, kk.y);
        const f16x8 av0 = frag4(vv0);
        const f16x8 av1 = frag4(vv1);

        f32x16 d = __builtin_amdgcn_mfma_f32_32x32x16_f16(ak, bq, zc, 0, 0, 0);

        // preload next tile (last iter reads in-bounds pad; unused)
        kk  = *(const uint2*)(lds + kaddr); kaddr += kstep;
        vv0 = *(const uint4*)(lds + vaddr);
        vv1 = *(const uint4*)(lds + vaddr + 32); vaddr += vstep;

        float p[16];
        #pragma unroll
        for (int r = 0; r < 16; ++r) p[r] = fast_exp2(d[r]);

        const int pk01 = cvtpk(p[0],  p[1]),  pk23 = cvtpk(p[2],  p[3]);
        const int pk45 = cvtpk(p[4],  p[5]),  pk67 = cvtpk(p[6],  p[7]);
        const int pk89 = cvtpk(p[8],  p[9]),  pkAB = cvtpk(p[10], p[11]);
        const int pkCD = cvtpk(p[12], p[13]), pkEF = cvtpk(p[14], p[15]);

        int B0, B1, B2, B3, C0, C1, C2, C3;
        swap32(pk01, pk45, lane, B0, B2);
        swap32(pk23, pk67, lane, B1, B3);
        swap32(pk89, pkCD, lane, C0, C2);
        swap32(pkAB, pkEF, lane, C1, C3);

        const f16x8 bp0 = fragi(B0, B1, B2, B3);   // P~^T, j 0..15
        const f16x8 bp1 = fragi(C0, C1, C2, C3);   // P~^T, j 16..31

        oacc = __builtin_amdgcn_mfma_f32_32x32x16_f16(av0, bp0, oacc, 0, 0, 0);
        oacc = __builtin_amdgcn_mfma_f32_32x32x16_f16(av1, bp1, oacc, 0, 0, 0);
    }

    // l sits in reg0 of lanes>=32 (row c=4); bring to lanes<32.
    union { float f; int i; } u0; u0.f = oacc[0];
    int s0i, s1i;
    swap32(u0.i, u0.i, lane, s0i, s1i);
    union { int i; float f; } ul; ul.i = s1i;
    if (lane < 32) {
        const int idx = jc * BHS + bh * SS + iblock * 32 + lane;
        pacc[idx] = make_float4(oacc[0], oacc[1], oacc[2], oacc[3]);
        pl[idx]   = ul.f;
    }
}

// ---------------------------------------------------------------------------
// Kernel 3: epilogue. Merge j-chunks (plain sums — no shift), normalize,
// then o @ Wo^T + bo, channel softmax, trend, seasonal.
// ---------------------------------------------------------------------------
__global__ __launch_bounds__(256) void k_epilogue(
    const float* __restrict__ x,      // [B,S]
    const float* __restrict__ Wo,     // [8,8]
    const float* __restrict__ bo,     // [8]
    const float4* __restrict__ pacc,
    const float* __restrict__ pl,
    const float4* __restrict__ mmws,
    float* __restrict__ out)          // seasonal [B*S] then trend [B*S]
{
    const int pos = blockIdx.x * 256 + threadIdx.x;  // = b*S + s
    const int b = pos / SS;
    const int s = pos % SS;

    float ov[8];
    #pragma unroll
    for (int h = 0; h < SH; ++h) {
        const int base = (b * SH + h) * SS + s;
        float lsum = 0.f, ax = 0.f, ay = 0.f, az = 0.f, aw = 0.f;
        #pragma unroll
        for (int jc = 0; jc < JCH; ++jc) {
            const float4 pa = pacc[jc * BHS + base];
            lsum += pl[jc * BHS + base];
            ax += pa.x; ay += pa.y; az += pa.z; aw += pa.w;
        }
        const float inv = 1.0f / lsum;
        ov[h * 4 + 0] = ax * inv;
        ov[h * 4 + 1] = ay * inv;
        ov[h * 4 + 2] = az * inv;
        ov[h * 4 + 3] = aw * inv;
    }

    float g[8];
    float m = -1e30f;
    #pragma unroll
    for (int e = 0; e < 8; ++e) {
        float acc = bo[e];
        #pragma unroll
        for (int f = 0; f < 8; ++f) acc += ov[f] * Wo[e * 8 + f];
        g[e] = acc;
        m = fmaxf(m, acc);
    }
    float l = 0.0f;
    #pragma unroll
    for (int e = 0; e < 8; ++e) { g[e] = __expf(g[e] - m); l += g[e]; }
    const float inv = 1.0f / l;

    const float4 mm0 = mmws[pos * 2 + 0];
    const float4 mm1 = mmws[pos * 2 + 1];
    const float mv[8] = {mm0.x, mm0.y, mm0.z, mm0.w, mm1.x, mm1.y, mm1.z, mm1.w};

    float trend = 0.0f;
    #pragma unroll
    for (int e = 0; e < 8; ++e) trend += g[e] * inv * mv[e];

    out[pos]           = x[pos] - trend;   // seasonal
    out[SB * SS + pos] = trend;            // trend
}

extern "C" void kernel_launch(void* const* d_in, const int* in_sizes, int n_in,
                              void* d_out, int out_size, void* d_ws, size_t ws_size,
                              hipStream_t stream) {
    const float* x  = (const float*)d_in[0];
    const float* Wq = (const float*)d_in[1];
    const float* Wk = (const float*)d_in[2];
    const float* Wv = (const float*)d_in[3];
    const float* Wo = (const float*)d_in[4];
    const float* bo = (const float*)d_in[5];

    uint2*     qws16 = (uint2*)d_ws;                        // 1 MB
    uint2*     kws16 = qws16 + BHS;                         // 1 MB
    _Float16*  vtg   = (_Float16*)(kws16 + BHS);            // 1 MB  [bh][4][S]
    float4*    mmws  = (float4*)(vtg + 4 * BHS);            // 2 MB
    float4*    pacc  = mmws + SB * SS * 2;                  // JCH*2 MB = 4 MB
    float*     pl    = (float*)(pacc + JCH * BHS);          // JCH*0.5 MB = 1 MB

    k_ma_qkv<<<SB * (SS / 256), 256, 0, stream>>>(x, Wq, Wk, Wv, qws16, kws16, vtg, mmws);
    k_attn<<<SB * SH * 16 * JCH, 256, 0, stream>>>(qws16, kws16, (const unsigned*)vtg, pacc, pl);
    k_epilogue<<<(SB * SS) / 256, 256, 0, stream>>>(x, Wo, bo, pacc, pl, mmws, (float*)d_out);
}

// Round 15
// 50.754 us; speedup vs baseline: 1.1137x; 1.1137x over previous
//
#include <hip/hip_runtime.h>

#define SB 32      // batch
#define SS 2048    // sequence
#define SH 2       // heads
#define SD 4       // head dim
#define SE 8       // embed

#define LOG2E 1.44269504f

typedef float    f32x16 __attribute__((ext_vector_type(16)));
typedef _Float16 f16x8  __attribute__((ext_vector_type(8)));

static __device__ __forceinline__ float fast_exp2(float x) {
#if __has_builtin(__builtin_amdgcn_exp2f)
    return __builtin_amdgcn_exp2f(x);
#else
    return exp2f(x);
#endif
}

static __device__ __forceinline__ int cvtpk(float a, float b) {
    auto h = __builtin_amdgcn_cvt_pkrtz(a, b);
    union { decltype(h) hh; int i; } u; u.hh = h; return u.i;
}

// exchange register halves across the lane<32 / lane>=32 boundary
static __device__ __forceinline__ void swap32(int a, int b, int lane, int& r0, int& r1) {
#if __has_builtin(__builtin_amdgcn_permlane32_swap)
    auto r = __builtin_amdgcn_permlane32_swap(a, b, false, false);
    r0 = r[0]; r1 = r[1];
#else
    const int blo = __builtin_amdgcn_ds_bpermute((lane & 31) << 2, b);
    const int ahi = __builtin_amdgcn_ds_bpermute(((lane ^ 32) & 63) << 2, a);
    r0 = (lane < 32) ? a : blo;
    r1 = (lane < 32) ? ahi : b;
#endif
}

static __device__ __forceinline__ f16x8 frag2(unsigned x, unsigned y) {
    union { unsigned u[4]; f16x8 h; } c;
    c.u[0] = x; c.u[1] = y; c.u[2] = 0; c.u[3] = 0; return c.h;
}
static __device__ __forceinline__ f16x8 frag4(uint4 v) {
    union { uint4 u; f16x8 h; } c; c.u = v; return c.h;
}
static __device__ __forceinline__ f16x8 fragi(int a, int b, int c_, int d) {
    union { int u[4]; f16x8 h; } c;
    c.u[0] = a; c.u[1] = b; c.u[2] = c_; c.u[3] = d; return c.h;
}

union u32h2 { unsigned u; _Float16 h[2]; };
static __device__ __forceinline__ unsigned packh2(float a, float b) {
    u32h2 c; c.h[0] = (_Float16)a; c.h[1] = (_Float16)b; return c.u;
}

// ---------------------------------------------------------------------------
// Kernel 1: moving averages + QKV projection. q (pre-scaled by log2e/sqrt(D))
// and k packed to f16 (uint2/row); V written TRANSPOSED as f16 rows
// VTg[bh][c=0..3][s]. No softmax shift anywhere: it cancels exactly, and
// scores are small enough that exp2 stays in f32/f16 range.
// ---------------------------------------------------------------------------
__global__ __launch_bounds__(256) void k_ma_qkv(
    const float* __restrict__ x,      // [B,S]
    const float* __restrict__ Wq,     // [4,4] row-major W[e*4+d]
    const float* __restrict__ Wk,
    const float* __restrict__ Wv,
    uint2* __restrict__ qws16,        // [B*H*S] packed f16 {q01,q23}
    uint2* __restrict__ kws16,        // [B*H*S]
    _Float16* __restrict__ vtg,       // [B*H][4][S] V transposed, f16
    float4* __restrict__ mmws)        // [B*S*2]
{
    __shared__ float xs[272];

    const int tile = blockIdx.x % (SS / 256);
    const int b    = blockIdx.x / (SS / 256);
    const int s0   = tile * 256;
    const float* xrow = x + b * SS;

    for (int i = threadIdx.x; i < 272; i += 256) {
        int idx = s0 - 8 + i;
        idx = min(max(idx, 0), SS - 1);
        xs[i] = xrow[idx];
    }
    __syncthreads();

    const int t = threadIdx.x;
    const int s = s0 + t;

    float mmv[8];
    float c = xs[8 + t];
    #pragma unroll
    for (int h = 1; h <= 8; ++h) {
        c += xs[8 + t - h] + xs[8 + t + h];
        mmv[h - 1] = c * (1.0f / (float)(2 * h + 1));
    }

    mmws[(b * SS + s) * 2 + 0] = make_float4(mmv[0], mmv[1], mmv[2], mmv[3]);
    mmws[(b * SS + s) * 2 + 1] = make_float4(mmv[4], mmv[5], mmv[6], mmv[7]);

    const float qscale = 0.5f * LOG2E;  // 1/sqrt(D) * log2(e)
    #pragma unroll
    for (int h = 0; h < SH; ++h) {
        const float t0 = mmv[h * 4 + 0];
        const float t1 = mmv[h * 4 + 1];
        const float t2 = mmv[h * 4 + 2];
        const float t3 = mmv[h * 4 + 3];
        float q[4], k[4], v[4];
        #pragma unroll
        for (int e = 0; e < 4; ++e) {
            q[e] = (t0 * Wq[e * 4 + 0] + t1 * Wq[e * 4 + 1] +
                    t2 * Wq[e * 4 + 2] + t3 * Wq[e * 4 + 3]) * qscale;
            k[e] =  t0 * Wk[e * 4 + 0] + t1 * Wk[e * 4 + 1] +
                    t2 * Wk[e * 4 + 2] + t3 * Wk[e * 4 + 3];
            v[e] =  t0 * Wv[e * 4 + 0] + t1 * Wv[e * 4 + 1] +
                    t2 * Wv[e * 4 + 2] + t3 * Wv[e * 4 + 3];
        }
        const int bh  = b * SH + h;
        const int idx = bh * SS + s;
        qws16[idx] = make_uint2(packh2(q[0], q[1]), packh2(q[2], q[3]));
        kws16[idx] = make_uint2(packh2(k[0], k[1]), packh2(k[2], k[3]));
        #pragma unroll
        for (int e = 0; e < 4; ++e)
            vtg[(bh * 4 + e) * SS + s] = (_Float16)v[e];
    }
}

// ---------------------------------------------------------------------------
// Kernel 2: MFMA flash attention with 2-stage software pipeline.
// R13 geometry (full SS per block, 4 blocks/CU — occupancy experiments in
// both directions (R14 up, R9/R11 down) show wave count is not the lever;
// the per-wave QK->exp->PV serial chain is). Here tile t+1's QK mfma is
// issued BEFORE tile t's exp/cvt/swap/PV, so the matrix pipe and the
// VALU/trans pipes overlap; #pragma unroll 2 double-buffers d without moves.
//   S^T = mfma(A=K-tile, B=Q); P~ = exp2(S^T)  (no shift — cancels);
//   O^T += mfma(A=V^T(+ones row -> l), B=P~ via cvt_pkrtz+permlane32_swap)
// Grid = B*H * 16 blocks, 4 waves/block; K prefetch 2 tiles ahead, V 1.
// ---------------------------------------------------------------------------
#define LDS_K    0
#define LDS_VT   16384
#define VT_STRIDE 4112          // (2048+8) f16 -> breaks bank alignment
#define LDS_Z    36944          // 128 B zero slot (padded-lane reads)
#define LDS_SIZE 37376

__global__ __launch_bounds__(256) void k_attn(
    const uint2* __restrict__ qws16,
    const uint2* __restrict__ kws16,
    const unsigned* __restrict__ vtg,   // u32 view of VT f16 [bh][4][SS]
    float4* __restrict__ ows)           // [B*H*S] normalized attention out
{
    __shared__ __align__(16) char lds[LDS_SIZE];

    const int t      = threadIdx.x;
    const int bh     = blockIdx.x >> 4;
    const int w      = t >> 6;
    const int iblock = (blockIdx.x & 15) * 4 + w;
    const int lane   = t & 63;
    const int c31    = lane & 31;

    // ---- stage K (16 KB: uint2 per key) ----
    const uint2* kg = kws16 + bh * SS;
    for (int i = t; i < SS; i += 256)
        *(uint2*)(lds + LDS_K + i * 8) = kg[i];
    // ---- stage V^T rows 0..3 (f16, padded row stride) ----
    const unsigned* vg = vtg + bh * 4 * (SS / 2);
    for (int i = t; i < 4 * (SS / 2); i += 256) {
        const int cc = i >> 10, col = i & 1023;
        *(unsigned*)(lds + LDS_VT + cc * VT_STRIDE + col * 4) = vg[i];
    }
    // ---- ones row (c = 4) for the l-accumulator ----
    for (int i = t; i < SS / 2; i += 256)
        *(unsigned*)(lds + LDS_VT + 4 * VT_STRIDE + i * 4) = 0x3C003C00u;
    // ---- zero slot ----
    if (t < 32) *(unsigned*)(lds + LDS_Z + t * 4) = 0u;
    __syncthreads();

    // Q B-frag (fixed per wave): lane holds col i=lane&31, k=d (lanes>=32 pad 0)
    uint2 qq = qws16[bh * SS + iblock * 32 + c31];
    if (lane >= 32) { qq.x = 0u; qq.y = 0u; }
    const f16x8 bq = frag2(qq.x, qq.y);

    // per-lane LDS addresses (padded lanes read the zero slot, never step)
    int kaddr = (lane < 32) ? (LDS_K + lane * 8) : LDS_Z;
    const int kstep = (lane < 32) ? 256 : 0;            // 32 keys * 8 B
    int vaddr = (c31 < 5) ? (LDS_VT + c31 * VT_STRIDE + (lane >> 5) * 16) : LDS_Z;
    const int vstep = (c31 < 5) ? 64 : 0;               // 32 j * 2 B

    f32x16 oacc = {0,0,0,0,0,0,0,0,0,0,0,0,0,0,0,0};
    const f32x16 zc = {0,0,0,0,0,0,0,0,0,0,0,0,0,0,0,0};

    // ---- pipeline prologue ----
    uint2 kk = *(const uint2*)(lds + kaddr); kaddr += kstep;        // K tile 0
    uint4 vv0 = *(const uint4*)(lds + vaddr);                       // V tile 0
    uint4 vv1 = *(const uint4*)(lds + vaddr + 32); vaddr += vstep;
    f32x16 d_cur = __builtin_amdgcn_mfma_f32_32x32x16_f16(frag2(kk.x, kk.y), bq, zc, 0, 0, 0);
    kk = *(const uint2*)(lds + kaddr); kaddr += kstep;              // K tile 1

    #pragma unroll 2
    for (int jt = 0; jt < SS / 32; ++jt) {
        const f16x8 av0 = frag4(vv0);       // V of tile jt
        const f16x8 av1 = frag4(vv1);

        // issue next tile's QK mfma FIRST (matrix pipe runs under the
        // exp/cvt/swap below). Last iteration computes on pad: discarded.
        f32x16 d_next = __builtin_amdgcn_mfma_f32_32x32x16_f16(frag2(kk.x, kk.y), bq, zc, 0, 0, 0);

        // prefetch K (tile jt+2) and V (tile jt+1); overruns stay in-bounds
        kk  = *(const uint2*)(lds + kaddr); kaddr += kstep;
        vv0 = *(const uint4*)(lds + vaddr);
        vv1 = *(const uint4*)(lds + vaddr + 32); vaddr += vstep;

        // softmax + PV of tile jt
        float p[16];
        #pragma unroll
        for (int r = 0; r < 16; ++r) p[r] = fast_exp2(d_cur[r]);

        const int pk01 = cvtpk(p[0],  p[1]),  pk23 = cvtpk(p[2],  p[3]);
        const int pk45 = cvtpk(p[4],  p[5]),  pk67 = cvtpk(p[6],  p[7]);
        const int pk89 = cvtpk(p[8],  p[9]),  pkAB = cvtpk(p[10], p[11]);
        const int pkCD = cvtpk(p[12], p[13]), pkEF = cvtpk(p[14], p[15]);

        int B0, B1, B2, B3, C0, C1, C2, C3;
        swap32(pk01, pk45, lane, B0, B2);
        swap32(pk23, pk67, lane, B1, B3);
        swap32(pk89, pkCD, lane, C0, C2);
        swap32(pkAB, pkEF, lane, C1, C3);

        const f16x8 bp0 = fragi(B0, B1, B2, B3);   // P~^T, j 0..15
        const f16x8 bp1 = fragi(C0, C1, C2, C3);   // P~^T, j 16..31

        oacc = __builtin_amdgcn_mfma_f32_32x32x16_f16(av0, bp0, oacc, 0, 0, 0);
        oacc = __builtin_amdgcn_mfma_f32_32x32x16_f16(av1, bp1, oacc, 0, 0, 0);

        d_cur = d_next;
    }

    // l sits in reg0 of lanes>=32 (row c=4); bring to lanes<32 and normalize.
    union { float f; int i; } u0; u0.f = oacc[0];
    int s0i, s1i;
    swap32(u0.i, u0.i, lane, s0i, s1i);
    union { int i; float f; } ul; ul.i = s1i;      // lanes<32: l from lane+32
    if (lane < 32) {
        const float inv = 1.0f / ul.f;
        ows[bh * SS + iblock * 32 + lane] =
            make_float4(oacc[0] * inv, oacc[1] * inv, oacc[2] * inv, oacc[3] * inv);
    }
}

// ---------------------------------------------------------------------------
// Kernel 3: epilogue. O already normalized. o @ Wo^T + bo, channel softmax,
// trend, seasonal.
// ---------------------------------------------------------------------------
__global__ __launch_bounds__(256) void k_epilogue(
    const float* __restrict__ x,      // [B,S]
    const float* __restrict__ Wo,     // [8,8]
    const float* __restrict__ bo,     // [8]
    const float4* __restrict__ ows,
    const float4* __restrict__ mmws,
    float* __restrict__ out)          // seasonal [B*S] then trend [B*S]
{
    const int pos = blockIdx.x * 256 + threadIdx.x;  // = b*S + s
    const int b = pos / SS;
    const int s = pos % SS;

    const float4 o0 = ows[(b * SH + 0) * SS + s];
    const float4 o1 = ows[(b * SH + 1) * SS + s];
    const float ov[8] = {o0.x, o0.y, o0.z, o0.w, o1.x, o1.y, o1.z, o1.w};

    float g[8];
    float m = -1e30f;
    #pragma unroll
    for (int e = 0; e < 8; ++e) {
        float acc = bo[e];
        #pragma unroll
        for (int f = 0; f < 8; ++f) acc += ov[f] * Wo[e * 8 + f];
        g[e] = acc;
        m = fmaxf(m, acc);
    }
    float l = 0.0f;
    #pragma unroll
    for (int e = 0; e < 8; ++e) { g[e] = __expf(g[e] - m); l += g[e]; }
    const float inv = 1.0f / l;

    const float4 mm0 = mmws[pos * 2 + 0];
    const float4 mm1 = mmws[pos * 2 + 1];
    const float mv[8] = {mm0.x, mm0.y, mm0.z, mm0.w, mm1.x, mm1.y, mm1.z, mm1.w};

    float trend = 0.0f;
    #pragma unroll
    for (int e = 0; e < 8; ++e) trend += g[e] * inv * mv[e];

    out[pos]           = x[pos] - trend;   // seasonal
    out[SB * SS + pos] = trend;            // trend
}

extern "C" void kernel_launch(void* const* d_in, const int* in_sizes, int n_in,
                              void* d_out, int out_size, void* d_ws, size_t ws_size,
                              hipStream_t stream) {
    const float* x  = (const float*)d_in[0];
    const float* Wq = (const float*)d_in[1];
    const float* Wk = (const float*)d_in[2];
    const float* Wv = (const float*)d_in[3];
    const float* Wo = (const float*)d_in[4];
    const float* bo = (const float*)d_in[5];

    uint2*     qws16 = (uint2*)d_ws;                        // 1 MB
    uint2*     kws16 = qws16 + SB * SH * SS;                // 1 MB
    _Float16*  vtg   = (_Float16*)(kws16 + SB * SH * SS);   // 1 MB  [bh][4][S]
    float4*    mmws  = (float4*)(vtg + SB * SH * 4 * SS);   // 2 MB
    float4*    ows   = mmws + SB * SS * 2;                  // 2 MB

    k_ma_qkv<<<SB * (SS / 256), 256, 0, stream>>>(x, Wq, Wk, Wv, qws16, kws16, vtg, mmws);
    k_attn<<<SB * SH * 16, 256, 0, stream>>>(qws16, kws16, (const unsigned*)vtg, ows);
    k_epilogue<<<(SB * SS) / 256, 256, 0, stream>>>(x, Wo, bo, ows, mmws, (float*)d_out);
}

// Round 16
// 48.056 us; speedup vs baseline: 1.1762x; 1.0561x over previous
//
#include <hip/hip_runtime.h>

#define SB 32      // batch
#define SS 2048    // sequence
#define SH 2       // heads
#define SD 4       // head dim
#define SE 8       // embed

#define LOG2E 1.44269504f

typedef float    f32x16 __attribute__((ext_vector_type(16)));
typedef _Float16 f16x8  __attribute__((ext_vector_type(8)));

static __device__ __forceinline__ float fast_exp2(float x) {
#if __has_builtin(__builtin_amdgcn_exp2f)
    return __builtin_amdgcn_exp2f(x);
#else
    return exp2f(x);
#endif
}

static __device__ __forceinline__ int cvtpk(float a, float b) {
    auto h = __builtin_amdgcn_cvt_pkrtz(a, b);
    union { decltype(h) hh; int i; } u; u.hh = h; return u.i;
}

// exchange register halves across the lane<32 / lane>=32 boundary
static __device__ __forceinline__ void swap32(int a, int b, int lane, int& r0, int& r1) {
#if __has_builtin(__builtin_amdgcn_permlane32_swap)
    auto r = __builtin_amdgcn_permlane32_swap(a, b, false, false);
    r0 = r[0]; r1 = r[1];
#else
    const int blo = __builtin_amdgcn_ds_bpermute((lane & 31) << 2, b);
    const int ahi = __builtin_amdgcn_ds_bpermute(((lane ^ 32) & 63) << 2, a);
    r0 = (lane < 32) ? a : blo;
    r1 = (lane < 32) ? ahi : b;
#endif
}

static __device__ __forceinline__ f16x8 frag2(unsigned x, unsigned y) {
    union { unsigned u[4]; f16x8 h; } c;
    c.u[0] = x; c.u[1] = y; c.u[2] = 0; c.u[3] = 0; return c.h;
}
static __device__ __forceinline__ f16x8 frag4(uint4 v) {
    union { uint4 u; f16x8 h; } c; c.u = v; return c.h;
}
static __device__ __forceinline__ f16x8 fragi(int a, int b, int c_, int d) {
    union { int u[4]; f16x8 h; } c;
    c.u[0] = a; c.u[1] = b; c.u[2] = c_; c.u[3] = d; return c.h;
}

union u32h2 { unsigned u; _Float16 h[2]; };
static __device__ __forceinline__ unsigned packh2(float a, float b) {
    u32h2 c; c.h[0] = (_Float16)a; c.h[1] = (_Float16)b; return c.u;
}

// ---------------------------------------------------------------------------
// Kernel 1: moving averages + QKV projection (unchanged from R15).
// ---------------------------------------------------------------------------
__global__ __launch_bounds__(256) void k_ma_qkv(
    const float* __restrict__ x,      // [B,S]
    const float* __restrict__ Wq,     // [4,4] row-major W[e*4+d]
    const float* __restrict__ Wk,
    const float* __restrict__ Wv,
    uint2* __restrict__ qws16,        // [B*H*S] packed f16 {q01,q23}
    uint2* __restrict__ kws16,        // [B*H*S]
    _Float16* __restrict__ vtg,       // [B*H][4][S] V transposed, f16
    float4* __restrict__ mmws)        // [B*S*2]
{
    __shared__ float xs[272];

    const int tile = blockIdx.x % (SS / 256);
    const int b    = blockIdx.x / (SS / 256);
    const int s0   = tile * 256;
    const float* xrow = x + b * SS;

    for (int i = threadIdx.x; i < 272; i += 256) {
        int idx = s0 - 8 + i;
        idx = min(max(idx, 0), SS - 1);
        xs[i] = xrow[idx];
    }
    __syncthreads();

    const int t = threadIdx.x;
    const int s = s0 + t;

    float mmv[8];
    float c = xs[8 + t];
    #pragma unroll
    for (int h = 1; h <= 8; ++h) {
        c += xs[8 + t - h] + xs[8 + t + h];
        mmv[h - 1] = c * (1.0f / (float)(2 * h + 1));
    }

    mmws[(b * SS + s) * 2 + 0] = make_float4(mmv[0], mmv[1], mmv[2], mmv[3]);
    mmws[(b * SS + s) * 2 + 1] = make_float4(mmv[4], mmv[5], mmv[6], mmv[7]);

    const float qscale = 0.5f * LOG2E;  // 1/sqrt(D) * log2(e)
    #pragma unroll
    for (int h = 0; h < SH; ++h) {
        const float t0 = mmv[h * 4 + 0];
        const float t1 = mmv[h * 4 + 1];
        const float t2 = mmv[h * 4 + 2];
        const float t3 = mmv[h * 4 + 3];
        float q[4], k[4], v[4];
        #pragma unroll
        for (int e = 0; e < 4; ++e) {
            q[e] = (t0 * Wq[e * 4 + 0] + t1 * Wq[e * 4 + 1] +
                    t2 * Wq[e * 4 + 2] + t3 * Wq[e * 4 + 3]) * qscale;
            k[e] =  t0 * Wk[e * 4 + 0] + t1 * Wk[e * 4 + 1] +
                    t2 * Wk[e * 4 + 2] + t3 * Wk[e * 4 + 3];
            v[e] =  t0 * Wv[e * 4 + 0] + t1 * Wv[e * 4 + 1] +
                    t2 * Wv[e * 4 + 2] + t3 * Wv[e * 4 + 3];
        }
        const int bh  = b * SH + h;
        const int idx = bh * SS + s;
        qws16[idx] = make_uint2(packh2(q[0], q[1]), packh2(q[2], q[3]));
        kws16[idx] = make_uint2(packh2(k[0], k[1]), packh2(k[2], k[3]));
        #pragma unroll
        for (int e = 0; e < 4; ++e)
            vtg[(bh * 4 + e) * SS + s] = (_Float16)v[e];
    }
}

// ---------------------------------------------------------------------------
// Kernel 2: MFMA flash attention, DEPTH-2 QK pipeline with statically named
// A/B buffers (no d copy, no runtime indexing). R15's 1-deep pipeline was a
// perfect null (compiler had already done it); issue util is only ~24%, so
// waves stall on QK-mfma result latency (~150-250 cyc > the ~104 cyc of
// work a 1-deep window provides). Two tiles in flight give ~208+ cyc cover.
// s_setprio(1) wraps the PV mfma pairs (T5, +4-7% attn, m191).
//   S^T = mfma(A=K-tile, B=Q); P~ = exp2(S^T)  (no shift — cancels);
//   O^T += mfma(A=V^T(+ones row -> l), B=P~ via cvt_pkrtz+permlane32_swap)
// Grid = B*H * 16 blocks, 4 waves/block.
// ---------------------------------------------------------------------------
#define LDS_K    0
#define LDS_VT   16384
#define VT_STRIDE 4112          // (2048+8) f16 -> breaks bank alignment
#define LDS_Z    36944          // 128 B zero slot (padded-lane reads)
#define LDS_SIZE 37376
#define NT       (SS / 32)      // 64 j-tiles

__global__ __launch_bounds__(256, 4) void k_attn(
    const uint2* __restrict__ qws16,
    const uint2* __restrict__ kws16,
    const unsigned* __restrict__ vtg,   // u32 view of VT f16 [bh][4][SS]
    float4* __restrict__ ows)           // [B*H*S] normalized attention out
{
    __shared__ __align__(16) char lds[LDS_SIZE];

    const int t      = threadIdx.x;
    const int bh     = blockIdx.x >> 4;
    const int w      = t >> 6;
    const int iblock = (blockIdx.x & 15) * 4 + w;
    const int lane   = t & 63;
    const int c31    = lane & 31;

    // ---- stage K (16 KB: uint2 per key) ----
    const uint2* kg = kws16 + bh * SS;
    for (int i = t; i < SS; i += 256)
        *(uint2*)(lds + LDS_K + i * 8) = kg[i];
    // ---- stage V^T rows 0..3 (f16, padded row stride) ----
    const unsigned* vg = vtg + bh * 4 * (SS / 2);
    for (int i = t; i < 4 * (SS / 2); i += 256) {
        const int cc = i >> 10, col = i & 1023;
        *(unsigned*)(lds + LDS_VT + cc * VT_STRIDE + col * 4) = vg[i];
    }
    // ---- ones row (c = 4) for the l-accumulator ----
    for (int i = t; i < SS / 2; i += 256)
        *(unsigned*)(lds + LDS_VT + 4 * VT_STRIDE + i * 4) = 0x3C003C00u;
    // ---- zero slot ----
    if (t < 32) *(unsigned*)(lds + LDS_Z + t * 4) = 0u;
    __syncthreads();

    // Q B-frag (fixed per wave): lane holds col i=lane&31, k=d (lanes>=32 pad 0)
    uint2 qq = qws16[bh * SS + iblock * 32 + c31];
    if (lane >= 32) { qq.x = 0u; qq.y = 0u; }
    const f16x8 bq = frag2(qq.x, qq.y);

    // per-lane LDS addresses (padded lanes read the zero slot, never step)
    int kaddr = (lane < 32) ? (LDS_K + lane * 8) : LDS_Z;
    const int kstep = (lane < 32) ? 256 : 0;            // 32 keys * 8 B
    int vaddr = (c31 < 5) ? (LDS_VT + c31 * VT_STRIDE + (lane >> 5) * 16) : LDS_Z;
    const int vstep = (c31 < 5) ? 64 : 0;               // 32 j * 2 B

    f32x16 oacc = {0,0,0,0,0,0,0,0,0,0,0,0,0,0,0,0};
    const f32x16 zc = {0,0,0,0,0,0,0,0,0,0,0,0,0,0,0,0};

    // ---- prologue: tiles 0 (A) and 1 (B) in flight ----
    uint2 kkA = *(const uint2*)(lds + kaddr); kaddr += kstep;   // K[0]
    uint2 kkB = *(const uint2*)(lds + kaddr); kaddr += kstep;   // K[1]
    uint4 vvA0 = *(const uint4*)(lds + vaddr);                  // V[0]
    uint4 vvA1 = *(const uint4*)(lds + vaddr + 32); vaddr += vstep;
    f32x16 dA = __builtin_amdgcn_mfma_f32_32x32x16_f16(frag2(kkA.x, kkA.y), bq, zc, 0, 0, 0);
    kkA = *(const uint2*)(lds + kaddr); kaddr += kstep;         // K[2]
    f32x16 dB = __builtin_amdgcn_mfma_f32_32x32x16_f16(frag2(kkB.x, kkB.y), bq, zc, 0, 0, 0);
    kkB = *(const uint2*)(lds + kaddr); kaddr += kstep;         // K[3]
    uint4 vvB0 = *(const uint4*)(lds + vaddr);                  // V[1]
    uint4 vvB1 = *(const uint4*)(lds + vaddr + 32); vaddr += vstep;

    for (int jt = 0; jt < NT; jt += 2) {
        // ================= tile jt (A) =================
        {
            float p[16];
            #pragma unroll
            for (int r = 0; r < 16; ++r) p[r] = fast_exp2(dA[r]);

            // reissue A: scores for tile jt+2 (WAR after the exps read dA)
            dA = __builtin_amdgcn_mfma_f32_32x32x16_f16(frag2(kkA.x, kkA.y), bq, zc, 0, 0, 0);
            kkA = *(const uint2*)(lds + kaddr); kaddr += kstep;   // K[jt+4]

            const f16x8 avA0 = frag4(vvA0);
            const f16x8 avA1 = frag4(vvA1);
            vvA0 = *(const uint4*)(lds + vaddr);                  // V[jt+2]
            vvA1 = *(const uint4*)(lds + vaddr + 32); vaddr += vstep;

            const int pk01 = cvtpk(p[0],  p[1]),  pk23 = cvtpk(p[2],  p[3]);
            const int pk45 = cvtpk(p[4],  p[5]),  pk67 = cvtpk(p[6],  p[7]);
            const int pk89 = cvtpk(p[8],  p[9]),  pkAB = cvtpk(p[10], p[11]);
            const int pkCD = cvtpk(p[12], p[13]), pkEF = cvtpk(p[14], p[15]);

            int B0, B1, B2, B3, C0, C1, C2, C3;
            swap32(pk01, pk45, lane, B0, B2);
            swap32(pk23, pk67, lane, B1, B3);
            swap32(pk89, pkCD, lane, C0, C2);
            swap32(pkAB, pkEF, lane, C1, C3);

            __builtin_amdgcn_s_setprio(1);
            oacc = __builtin_amdgcn_mfma_f32_32x32x16_f16(avA0, fragi(B0, B1, B2, B3), oacc, 0, 0, 0);
            oacc = __builtin_amdgcn_mfma_f32_32x32x16_f16(avA1, fragi(C0, C1, C2, C3), oacc, 0, 0, 0);
            __builtin_amdgcn_s_setprio(0);
        }
        // ================= tile jt+1 (B) =================
        {
            float p[16];
            #pragma unroll
            for (int r = 0; r < 16; ++r) p[r] = fast_exp2(dB[r]);

            dB = __builtin_amdgcn_mfma_f32_32x32x16_f16(frag2(kkB.x, kkB.y), bq, zc, 0, 0, 0);
            kkB = *(const uint2*)(lds + kaddr); kaddr += kstep;   // K[jt+5]

            const f16x8 avB0 = frag4(vvB0);
            const f16x8 avB1 = frag4(vvB1);
            vvB0 = *(const uint4*)(lds + vaddr);                  // V[jt+3]
            vvB1 = *(const uint4*)(lds + vaddr + 32); vaddr += vstep;

            const int pk01 = cvtpk(p[0],  p[1]),  pk23 = cvtpk(p[2],  p[3]);
            const int pk45 = cvtpk(p[4],  p[5]),  pk67 = cvtpk(p[6],  p[7]);
            const int pk89 = cvtpk(p[8],  p[9]),  pkAB = cvtpk(p[10], p[11]);
            const int pkCD = cvtpk(p[12], p[13]), pkEF = cvtpk(p[14], p[15]);

            int B0, B1, B2, B3, C0, C1, C2, C3;
            swap32(pk01, pk45, lane, B0, B2);
            swap32(pk23, pk67, lane, B1, B3);
            swap32(pk89, pkCD, lane, C0, C2);
            swap32(pkAB, pkEF, lane, C1, C3);

            __builtin_amdgcn_s_setprio(1);
            oacc = __builtin_amdgcn_mfma_f32_32x32x16_f16(avB0, fragi(B0, B1, B2, B3), oacc, 0, 0, 0);
            oacc = __builtin_amdgcn_mfma_f32_32x32x16_f16(avB1, fragi(C0, C1, C2, C3), oacc, 0, 0, 0);
            __builtin_amdgcn_s_setprio(0);
        }
    }

    // l sits in reg0 of lanes>=32 (row c=4); bring to lanes<32 and normalize.
    union { float f; int i; } u0; u0.f = oacc[0];
    int s0i, s1i;
    swap32(u0.i, u0.i, lane, s0i, s1i);
    union { int i; float f; } ul; ul.i = s1i;      // lanes<32: l from lane+32
    if (lane < 32) {
        const float inv = 1.0f / ul.f;
        ows[bh * SS + iblock * 32 + lane] =
            make_float4(oacc[0] * inv, oacc[1] * inv, oacc[2] * inv, oacc[3] * inv);
    }
}

// ---------------------------------------------------------------------------
// Kernel 3: epilogue (unchanged). O already normalized.
// ---------------------------------------------------------------------------
__global__ __launch_bounds__(256) void k_epilogue(
    const float* __restrict__ x,      // [B,S]
    const float* __restrict__ Wo,     // [8,8]
    const float* __restrict__ bo,     // [8]
    const float4* __restrict__ ows,
    const float4* __restrict__ mmws,
    float* __restrict__ out)          // seasonal [B*S] then trend [B*S]
{
    const int pos = blockIdx.x * 256 + threadIdx.x;  // = b*S + s
    const int b = pos / SS;
    const int s = pos % SS;

    const float4 o0 = ows[(b * SH + 0) * SS + s];
    const float4 o1 = ows[(b * SH + 1) * SS + s];
    const float ov[8] = {o0.x, o0.y, o0.z, o0.w, o1.x, o1.y, o1.z, o1.w};

    float g[8];
    float m = -1e30f;
    #pragma unroll
    for (int e = 0; e < 8; ++e) {
        float acc = bo[e];
        #pragma unroll
        for (int f = 0; f < 8; ++f) acc += ov[f] * Wo[e * 8 + f];
        g[e] = acc;
        m = fmaxf(m, acc);
    }
    float l = 0.0f;
    #pragma unroll
    for (int e = 0; e < 8; ++e) { g[e] = __expf(g[e] - m); l += g[e]; }
    const float inv = 1.0f / l;

    const float4 mm0 = mmws[pos * 2 + 0];
    const float4 mm1 = mmws[pos * 2 + 1];
    const float mv[8] = {mm0.x, mm0.y, mm0.z, mm0.w, mm1.x, mm1.y, mm1.z, mm1.w};

    float trend = 0.0f;
    #pragma unroll
    for (int e = 0; e < 8; ++e) trend += g[e] * inv * mv[e];

    out[pos]           = x[pos] - trend;   // seasonal
    out[SB * SS + pos] = trend;            // trend
}

extern "C" void kernel_launch(void* const* d_in, const int* in_sizes, int n_in,
                              void* d_out, int out_size, void* d_ws, size_t ws_size,
                              hipStream_t stream) {
    const float* x  = (const float*)d_in[0];
    const float* Wq = (const float*)d_in[1];
    const float* Wk = (const float*)d_in[2];
    const float* Wv = (const float*)d_in[3];
    const float* Wo = (const float*)d_in[4];
    const float* bo = (const float*)d_in[5];

    uint2*     qws16 = (uint2*)d_ws;                        // 1 MB
    uint2*     kws16 = qws16 + SB * SH * SS;                // 1 MB
    _Float16*  vtg   = (_Float16*)(kws16 + SB * SH * SS);   // 1 MB  [bh][4][S]
    float4*    mmws  = (float4*)(vtg + SB * SH * 4 * SS);   // 2 MB
    float4*    ows   = mmws + SB * SS * 2;                  // 2 MB

    k_ma_qkv<<<SB * (SS / 256), 256, 0, stream>>>(x, Wq, Wk, Wv, qws16, kws16, vtg, mmws);
    k_attn<<<SB * SH * 16, 256, 0, stream>>>(qws16, kws16, (const unsigned*)vtg, ows);
    k_epilogue<<<(SB * SS) / 256, 256, 0, stream>>>(x, Wo, bo, ows, mmws, (float*)d_out);
}